// Round 5
// baseline (300.877 us; speedup 1.0000x reference)
//
#include <hip/hip_runtime.h>
#include <hip/hip_bf16.h>

#define HW 16384
#define NC 256
#define NO 64
#define NPM 1048576          // floats per (b, modality)
#define EPS_IN 1e-5f
#define DBLK 1024            // k_dots blocks.x (one 4KB window per modality each)
#define WIN 1024             // floats per modality per window

typedef float f32x4 __attribute__((ext_vector_type(4)));
typedef short bhalf8 __attribute__((ext_vector_type(8)));

static __device__ __forceinline__ short f2bf(float f){
  __bf16 h = (__bf16)f;
  return __builtin_bit_cast(short, h);
}

// ws float layout: [256,320) probs[b][m] ; [320,2368) stats[(b*64+o)*2+{s,q}] ;
//                  [8192, 8192+16*DBLK*10) block partials (no atomics)

__global__ void k_zero(float* ws){
  int i = blockIdx.x*256 + threadIdx.x;
  if (i < 2048) ws[320 + i] = 0.f;   // stats only
}

// Pass 1: Gram partials. One window per block; each wave streams one modality
// into LDS via global_load_lds (linear dest). No inter-window barrier chain:
// latency hidden by 16384 independent blocks. Per-batch skew breaks the
// 16MiB batch-stream aliasing.
__global__ void k_dots(const float* __restrict__ x, float* __restrict__ partials){
  __shared__ float lds[4][WIN];
  __shared__ float red[4][16];
  const int b = blockIdx.y, bx = blockIdx.x;
  const int tid = threadIdx.x;
  const int w = tid >> 6, lane = tid & 63;
  const int wi = (bx + b*67) & (DBLK-1);              // skewed window index
  const float* src = x + (size_t)b*4*NPM + (size_t)w*NPM + (size_t)wi*WIN + lane*4;

  #pragma unroll
  for (int li=0; li<4; li++){
    __builtin_amdgcn_global_load_lds(
        (const __attribute__((address_space(1))) void*)(src + li*256),
        (__attribute__((address_space(3))) void*)&lds[w][li*256],
        16, 0, 0);
  }
  __syncthreads();

  float4 vv[4];
  #pragma unroll
  for (int m=0;m<4;m++) vv[m] = *(const float4*)&lds[m][tid*4];
  float acc[10];
  int k=0;
  #pragma unroll
  for (int i=0;i<4;i++)
    #pragma unroll
    for (int j=i;j<4;j++,k++)
      acc[k] = vv[i].x*vv[j].x + vv[i].y*vv[j].y + vv[i].z*vv[j].z + vv[i].w*vv[j].w;

  // full-wave reduce, then cross-wave via LDS, one plain store (no atomics)
  #pragma unroll
  for (int kk=0;kk<10;kk++){
    float s = acc[kk];
    #pragma unroll
    for (int off=1; off<64; off<<=1) s += __shfl_xor(s, off, 64);
    acc[kk]=s;
  }
  if (lane==0){
    #pragma unroll
    for (int kk=0;kk<10;kk++) red[w][kk] = acc[kk];
  }
  __syncthreads();
  if (tid<10){
    float s = red[0][tid] + red[1][tid] + red[2][tid] + red[3][tid];
    partials[((size_t)b*DBLK + bx)*10 + tid] = s;
  }
}

// Pass 2: reduce DBLK partials per batch, cosine scores, softmax -> probs
__global__ void k_attn(const float* __restrict__ partials, float* __restrict__ probs){
  __shared__ float red[4][16];
  int b = blockIdx.x, tid = threadIdx.x;       // 256 threads
  int w = tid>>6, lane = tid&63;
  float a[10];
  #pragma unroll
  for (int kk=0;kk<10;kk++) a[kk]=0.f;
  #pragma unroll
  for (int r=0;r<DBLK/256;r++){
    const float* p = partials + ((size_t)b*DBLK + r*256 + tid)*10;
    #pragma unroll
    for (int kk=0;kk<10;kk++) a[kk]+=p[kk];
  }
  #pragma unroll
  for (int kk=0;kk<10;kk++){
    float s=a[kk];
    #pragma unroll
    for (int off=1;off<64;off<<=1) s+=__shfl_xor(s,off,64);
    a[kk]=s;
  }
  if (lane==0){
    #pragma unroll
    for (int kk=0;kk<10;kk++) red[w][kk]=a[kk];
  }
  __syncthreads();
  if (tid==0){
    float d[10];
    #pragma unroll
    for (int kk=0;kk<10;kk++) d[kk]=red[0][kk]+red[1][kk]+red[2][kk]+red[3][kk];
    float D[4][4];
    int k2=0;
    #pragma unroll
    for (int i=0;i<4;i++)
      #pragma unroll
      for (int j=i;j<4;j++,k2++){ D[i][j]=d[k2]; D[j][i]=d[k2]; }
    float nrm[4];
    #pragma unroll
    for (int m=0;m<4;m++) nrm[m]=fmaxf(sqrtf(D[m][m]),1e-8f);
    float sc[4];
    #pragma unroll
    for (int i=0;i<4;i++){
      float s=0.f;
      #pragma unroll
      for (int j=0;j<4;j++) s += D[i][j]/(nrm[i]*nrm[j]);
      sc[i] = -(s-1.0f);
    }
    float mx = fmaxf(fmaxf(sc[0],sc[1]), fmaxf(sc[2],sc[3]));
    float e[4], se=0.f;
    #pragma unroll
    for (int m=0;m<4;m++){ e[m]=expf(sc[m]-mx); se+=e[m]; }
    #pragma unroll
    for (int m=0;m<4;m++) probs[b*4+m]=e[m]/se;
  }
}

// GEMM: Y[b] = (W * prob[b]) @ X[b].  A register-resident, B gathered from global.
__launch_bounds__(256, 2)
__global__ void k_gemm(const float* __restrict__ x, const float* __restrict__ w,
                       const float* __restrict__ ws, float* __restrict__ y,
                       float* __restrict__ stats){
  const int b   = blockIdx.y;
  const int wid = threadIdx.x >> 6;
  const int lane = threadIdx.x & 63;
  const int l15 = lane & 15;
  const int lg  = lane >> 4;

  const float* probs = ws + 256 + b*4;
  float pm[4] = {probs[0], probs[1], probs[2], probs[3]};

  bhalf8 afrag[4][8];
  const float4* w4 = reinterpret_cast<const float4*>(w);
  #pragma unroll
  for (int rt=0; rt<4; rt++){
    int row = rt*16 + l15;
    #pragma unroll
    for (int ks=0; ks<8; ks++){
      float s = pm[ks>>1];
      float4 a0 = w4[row*64 + ks*8 + lg];
      float4 a1 = w4[row*64 + ks*8 + lg + 4];
      bhalf8 f;
      f[0]=f2bf(a0.x*s); f[1]=f2bf(a0.y*s); f[2]=f2bf(a0.z*s); f[3]=f2bf(a0.w*s);
      f[4]=f2bf(a1.x*s); f[5]=f2bf(a1.y*s); f[6]=f2bf(a1.z*s); f[7]=f2bf(a1.w*s);
      afrag[rt][ks] = f;
    }
  }

  const float* xb = x + (size_t)b*NC*HW;
  float sacc[4][4] = {{0}}, qacc[4][4] = {{0}};
  const int bxp = (blockIdx.x + b*5) & 31;     // per-batch skew vs channel alias
  const int base = bxp * 512;

  #pragma unroll 1
  for (int it=0; it<8; it++){
    int n0 = base + wid*16 + it*64;
    f32x4 acc[4];
    #pragma unroll
    for (int rt=0; rt<4; rt++) acc[rt] = (f32x4){0.f,0.f,0.f,0.f};

    #pragma unroll
    for (int ks=0; ks<8; ks++){
      bhalf8 bfr;
      #pragma unroll
      for (int eh=0; eh<2; eh++)
        #pragma unroll
        for (int el=0; el<4; el++){
          int c = ks*32 + lg*4 + el + eh*16;
          bfr[eh*4+el] = f2bf(xb[(size_t)c*HW + n0 + l15]);
        }
      #pragma unroll
      for (int rt=0; rt<4; rt++)
        acc[rt] = __builtin_amdgcn_mfma_f32_16x16x32_bf16(afrag[rt][ks], bfr, acc[rt], 0, 0, 0);
    }

    size_t ybase = ((size_t)b*NO)*HW + n0 + l15;
    #pragma unroll
    for (int rt=0; rt<4; rt++){
      #pragma unroll
      for (int r=0; r<4; r++){
        int o = rt*16 + lg*4 + r;
        float v = acc[rt][r];
        y[ybase + (size_t)o*HW] = v;
        sacc[rt][r] += v;
        qacc[rt][r] += v*v;
      }
    }
  }

  #pragma unroll
  for (int rt=0; rt<4; rt++){
    #pragma unroll
    for (int r=0; r<4; r++){
      float s = sacc[rt][r], q = qacc[rt][r];
      #pragma unroll
      for (int off=1; off<16; off<<=1){
        s += __shfl_xor(s, off, 64);
        q += __shfl_xor(q, off, 64);
      }
      if (l15 == 0){
        int o = rt*16 + lg*4 + r;
        atomicAdd(&stats[(b*NO + o)*2],     s);
        atomicAdd(&stats[(b*NO + o)*2 + 1], q);
      }
    }
  }
}

__global__ void k_norm(float* __restrict__ y, const float* __restrict__ stats){
  int bo = blockIdx.x;
  float s = stats[bo*2], q = stats[bo*2+1];
  float mean = s * (1.f/HW);
  float var  = q * (1.f/HW) - mean*mean;
  float inv  = rsqrtf(var + EPS_IN);
  float4* yp = reinterpret_cast<float4*>(y) + (size_t)bo*(HW/4);
  #pragma unroll 4
  for (int i = threadIdx.x; i < HW/4; i += 256){
    float4 v = yp[i];
    v.x = fmaxf((v.x-mean)*inv, 0.f);
    v.y = fmaxf((v.y-mean)*inv, 0.f);
    v.z = fmaxf((v.z-mean)*inv, 0.f);
    v.w = fmaxf((v.w-mean)*inv, 0.f);
    yp[i] = v;
  }
}

extern "C" void kernel_launch(void* const* d_in, const int* in_sizes, int n_in,
                              void* d_out, int out_size, void* d_ws, size_t ws_size,
                              hipStream_t stream){
  const float* x = (const float*)d_in[0];
  const float* w = (const float*)d_in[1];
  float* out = (float*)d_out;
  float* ws  = (float*)d_ws;
  float* partials = ws + 8192;
  float* probs    = ws + 256;
  float* stats    = ws + 320;

  k_zero<<<dim3(8),        dim3(256), 0, stream>>>(ws);
  k_dots<<<dim3(DBLK,16),  dim3(256), 0, stream>>>(x, partials);
  k_attn<<<dim3(16),       dim3(256), 0, stream>>>(partials, probs);
  k_gemm<<<dim3(32,16),    dim3(256), 0, stream>>>(x, w, ws, out, stats);
  k_norm<<<dim3(1024),     dim3(256), 0, stream>>>(out, stats);
}

// Round 7
// 237.754 us; speedup vs baseline: 1.2655x; 1.2655x over previous
//
#include <hip/hip_runtime.h>
#include <hip/hip_bf16.h>

#define HW 16384
#define NC 256
#define NO 64
#define NPM 1048576          // floats per (b, modality)
#define EPS_IN 1e-5f
#define DBLK 1024            // k_dots blocks.x
#define WIN 1024             // floats per modality per window
#define GPX 64               // pixels per k_gemm block

typedef float f32x4 __attribute__((ext_vector_type(4)));
typedef short bhalf8 __attribute__((ext_vector_type(8)));

static __device__ __forceinline__ short f2bf(float f){
  __bf16 h = (__bf16)f;
  return __builtin_bit_cast(short, h);
}

// ws float layout: [256,320) probs[b][m] ; [320,2368) stats[(b*64+o)*2+{s,q}] ;
//                  [8192, 8192+16*DBLK*10) block partials (no atomics)

__global__ void k_zero(float* ws){
  int i = blockIdx.x*256 + threadIdx.x;
  if (i < 2048) ws[320 + i] = 0.f;   // stats only
}

// Pass 1: Gram partials. One window per block; each wave streams one modality
// into LDS via global_load_lds (linear dest). Latency hidden by 16384
// independent blocks; per-batch skew breaks 16MiB stream aliasing.
__global__ void k_dots(const float* __restrict__ x, float* __restrict__ partials){
  __shared__ float lds[4][WIN];
  __shared__ float red[4][16];
  const int b = blockIdx.y, bx = blockIdx.x;
  const int tid = threadIdx.x;
  const int w = tid >> 6, lane = tid & 63;
  const int wi = (bx + b*67) & (DBLK-1);              // skewed window index
  const float* src = x + (size_t)b*4*NPM + (size_t)w*NPM + (size_t)wi*WIN + lane*4;

  #pragma unroll
  for (int li=0; li<4; li++){
    __builtin_amdgcn_global_load_lds(
        (const __attribute__((address_space(1))) void*)(src + li*256),
        (__attribute__((address_space(3))) void*)&lds[w][li*256],
        16, 0, 0);
  }
  __syncthreads();

  float4 vv[4];
  #pragma unroll
  for (int m=0;m<4;m++) vv[m] = *(const float4*)&lds[m][tid*4];
  float acc[10];
  int k=0;
  #pragma unroll
  for (int i=0;i<4;i++)
    #pragma unroll
    for (int j=i;j<4;j++,k++)
      acc[k] = vv[i].x*vv[j].x + vv[i].y*vv[j].y + vv[i].z*vv[j].z + vv[i].w*vv[j].w;

  #pragma unroll
  for (int kk=0;kk<10;kk++){
    float s = acc[kk];
    #pragma unroll
    for (int off=1; off<64; off<<=1) s += __shfl_xor(s, off, 64);
    acc[kk]=s;
  }
  if (lane==0){
    #pragma unroll
    for (int kk=0;kk<10;kk++) red[w][kk] = acc[kk];
  }
  __syncthreads();
  if (tid<10){
    float s = red[0][tid] + red[1][tid] + red[2][tid] + red[3][tid];
    partials[((size_t)b*DBLK + bx)*10 + tid] = s;
  }
}

// Pass 2: reduce DBLK partials per batch, cosine scores, softmax -> probs
__global__ void k_attn(const float* __restrict__ partials, float* __restrict__ probs){
  __shared__ float red[4][16];
  int b = blockIdx.x, tid = threadIdx.x;       // 256 threads
  int w = tid>>6, lane = tid&63;
  float a[10];
  #pragma unroll
  for (int kk=0;kk<10;kk++) a[kk]=0.f;
  #pragma unroll
  for (int r=0;r<DBLK/256;r++){
    const float* p = partials + ((size_t)b*DBLK + r*256 + tid)*10;
    #pragma unroll
    for (int kk=0;kk<10;kk++) a[kk]+=p[kk];
  }
  #pragma unroll
  for (int kk=0;kk<10;kk++){
    float s=a[kk];
    #pragma unroll
    for (int off=1;off<64;off<<=1) s+=__shfl_xor(s,off,64);
    a[kk]=s;
  }
  if (lane==0){
    #pragma unroll
    for (int kk=0;kk<10;kk++) red[w][kk]=a[kk];
  }
  __syncthreads();
  if (tid==0){
    float d[10];
    #pragma unroll
    for (int kk=0;kk<10;kk++) d[kk]=red[0][kk]+red[1][kk]+red[2][kk]+red[3][kk];
    float D[4][4];
    int k2=0;
    #pragma unroll
    for (int i=0;i<4;i++)
      #pragma unroll
      for (int j=i;j<4;j++,k2++){ D[i][j]=d[k2]; D[j][i]=d[k2]; }
    float nrm[4];
    #pragma unroll
    for (int m=0;m<4;m++) nrm[m]=fmaxf(sqrtf(D[m][m]),1e-8f);
    float sc[4];
    #pragma unroll
    for (int i=0;i<4;i++){
      float s=0.f;
      #pragma unroll
      for (int j=0;j<4;j++) s += D[i][j]/(nrm[i]*nrm[j]);
      sc[i] = -(s-1.0f);
    }
    float mx = fmaxf(fmaxf(sc[0],sc[1]), fmaxf(sc[2],sc[3]));
    float e[4], se=0.f;
    #pragma unroll
    for (int m=0;m<4;m++){ e[m]=expf(sc[m]-mx); se+=e[m]; }
    #pragma unroll
    for (int m=0;m<4;m++) probs[b*4+m]=e[m]/se;
  }
}

// GEMM: Y[b] = (W * prob[b]) @ X[b].
// One X-tile [256ch][64px] (64KB LDS) per block via global_load_lds; 4096
// independent blocks (2 resident/CU) overlap staging and compute across
// blocks. B-frags from LDS; A (weights) register-resident from L2.
__launch_bounds__(256, 2)
__global__ void k_gemm(const float* __restrict__ x, const float* __restrict__ w,
                       const float* __restrict__ ws, float* __restrict__ y,
                       float* __restrict__ stats){
  __shared__ float xt[NC][GPX];     // 64 KB
  __shared__ float sred[128];
  const int b   = blockIdx.y;
  const int px0 = blockIdx.x * GPX;
  const int tid = threadIdx.x;
  const int wid = tid >> 6;
  const int lane = tid & 63;
  const int l15 = lane & 15;
  const int lg  = lane >> 4;

  if (tid < 128) sred[tid] = 0.f;

  // A fragments: row = rt*16 + l15; k-map (lg,e) -> c = ks*32 + 4*lg + (e&3) + 16*(e>>2)
  const float* probs = ws + 256 + b*4;
  float pm[4] = {probs[0], probs[1], probs[2], probs[3]};
  bhalf8 afrag[4][8];
  const float4* w4 = reinterpret_cast<const float4*>(w);
  #pragma unroll
  for (int rt=0; rt<4; rt++){
    int row = rt*16 + l15;
    #pragma unroll
    for (int ks=0; ks<8; ks++){
      float s = pm[ks>>1];
      float4 a0 = w4[row*64 + ks*8 + lg];
      float4 a1 = w4[row*64 + ks*8 + lg + 4];
      bhalf8 f;
      f[0]=f2bf(a0.x*s); f[1]=f2bf(a0.y*s); f[2]=f2bf(a0.z*s); f[3]=f2bf(a0.w*s);
      f[4]=f2bf(a1.x*s); f[5]=f2bf(a1.y*s); f[6]=f2bf(a1.z*s); f[7]=f2bf(a1.w*s);
      afrag[rt][ks] = f;
    }
  }

  // stage X tile: wave wid stages channels [wid*64, wid*64+64)
  {
    const float* src0 = x + (size_t)b*NC*HW + ((size_t)(wid*64) + (lane>>4))*HW
                          + px0 + (lane&15)*4;
    #pragma unroll
    for (int j=0; j<16; j++){
      __builtin_amdgcn_global_load_lds(
          (const __attribute__((address_space(1))) void*)(src0 + (size_t)(j*4)*HW),
          (__attribute__((address_space(3))) void*)&xt[wid*64 + j*4][0],
          16, 0, 0);
    }
  }
  __syncthreads();

  f32x4 acc[4];
  #pragma unroll
  for (int rt=0; rt<4; rt++) acc[rt] = (f32x4){0.f,0.f,0.f,0.f};

  #pragma unroll
  for (int ks=0; ks<8; ks++){
    bhalf8 bfr;
    #pragma unroll
    for (int eh=0; eh<2; eh++)
      #pragma unroll
      for (int el=0; el<4; el++){
        int c = ks*32 + lg*4 + el + eh*16;
        bfr[eh*4+el] = f2bf(xt[c][wid*16 + l15]);
      }
    #pragma unroll
    for (int rt=0; rt<4; rt++)
      acc[rt] = __builtin_amdgcn_mfma_f32_16x16x32_bf16(afrag[rt][ks], bfr, acc[rt], 0, 0, 0);
  }

  // C/D layout (verified): row = (lane>>4)*4 + reg, col = lane&15
  size_t ybase = ((size_t)b*NO)*HW + px0 + wid*16 + l15;
  #pragma unroll
  for (int rt=0; rt<4; rt++){
    #pragma unroll
    for (int r=0; r<4; r++){
      int o = rt*16 + lg*4 + r;
      float v = acc[rt][r];
      y[ybase + (size_t)o*HW] = v;
      float s = v, q = v*v;
      #pragma unroll
      for (int off=1; off<16; off<<=1){
        s += __shfl_xor(s, off, 64);
        q += __shfl_xor(q, off, 64);
      }
      if (l15 == 0){
        atomicAdd(&sred[o*2],     s);
        atomicAdd(&sred[o*2 + 1], q);
      }
    }
  }
  __syncthreads();
  if (tid < 128) atomicAdd(&stats[b*128 + tid], sred[tid]);
}

__global__ void k_norm(float* __restrict__ y, const float* __restrict__ stats){
  int bo = blockIdx.x;
  float s = stats[bo*2], q = stats[bo*2+1];
  float mean = s * (1.f/HW);
  float var  = q * (1.f/HW) - mean*mean;
  float inv  = rsqrtf(var + EPS_IN);
  float4* yp = reinterpret_cast<float4*>(y) + (size_t)bo*(HW/4);
  #pragma unroll 4
  for (int i = threadIdx.x; i < HW/4; i += 256){
    float4 v = yp[i];
    v.x = fmaxf((v.x-mean)*inv, 0.f);
    v.y = fmaxf((v.y-mean)*inv, 0.f);
    v.z = fmaxf((v.z-mean)*inv, 0.f);
    v.w = fmaxf((v.w-mean)*inv, 0.f);
    yp[i] = v;
  }
}

extern "C" void kernel_launch(void* const* d_in, const int* in_sizes, int n_in,
                              void* d_out, int out_size, void* d_ws, size_t ws_size,
                              hipStream_t stream){
  const float* x = (const float*)d_in[0];
  const float* w = (const float*)d_in[1];
  float* out = (float*)d_out;
  float* ws  = (float*)d_ws;
  float* partials = ws + 8192;
  float* probs    = ws + 256;
  float* stats    = ws + 320;

  k_zero<<<dim3(8),          dim3(256), 0, stream>>>(ws);
  k_dots<<<dim3(DBLK,16),    dim3(256), 0, stream>>>(x, partials);
  k_attn<<<dim3(16),         dim3(256), 0, stream>>>(partials, probs);
  k_gemm<<<dim3(HW/GPX,16),  dim3(256), 0, stream>>>(x, w, ws, out, stats);
  k_norm<<<dim3(1024),       dim3(256), 0, stream>>>(out, stats);
}

// Round 9
// 214.772 us; speedup vs baseline: 1.4009x; 1.1070x over previous
//
#include <hip/hip_runtime.h>
#include <hip/hip_bf16.h>

#define HW 16384
#define NC 256
#define NO 64
#define NPM 1048576          // floats per (b, modality)
#define EPS_IN 1e-5f
#define DBLK 1024            // k_dots blocks.x
#define WIN 1024             // floats per modality per window
#define SPX 256              // pixels per k_gemm block window
#define SCH 32               // channels per staged chunk (one k-slice of 32)
#define NCHK 8               // 256 / SCH
#define PAD 4                // floats of row padding in LDS

typedef float f32x4 __attribute__((ext_vector_type(4)));
typedef short bhalf8 __attribute__((ext_vector_type(8)));

static __device__ __forceinline__ short f2bf(float f){
  __bf16 h = (__bf16)f;
  return __builtin_bit_cast(short, h);
}

// ws float layout: [256,320) probs[b][m] ; [320,2368) stats[(b*64+o)*2+{s,q}] ;
//                  [8192, +16*DBLK*10) block partials

__global__ void k_zero(float* ws){
  int i = blockIdx.x*256 + threadIdx.x;
  if (i < 2048) ws[320 + i] = 0.f;   // stats only
}

// Pass 1: Gram partials. One window per block via global_load_lds (linear dest);
// latency hidden by 16384 independent blocks; per-batch skew vs stream aliasing.
__global__ void k_dots(const float* __restrict__ x, float* __restrict__ partials){
  __shared__ float lds[4][WIN];
  __shared__ float red[4][16];
  const int b = blockIdx.y, bx = blockIdx.x;
  const int tid = threadIdx.x;
  const int w = tid >> 6, lane = tid & 63;
  const int wi = (bx + b*67) & (DBLK-1);
  const float* src = x + (size_t)b*4*NPM + (size_t)w*NPM + (size_t)wi*WIN + lane*4;

  #pragma unroll
  for (int li=0; li<4; li++){
    __builtin_amdgcn_global_load_lds(
        (const __attribute__((address_space(1))) void*)(src + li*256),
        (__attribute__((address_space(3))) void*)&lds[w][li*256],
        16, 0, 0);
  }
  __syncthreads();

  float4 vv[4];
  #pragma unroll
  for (int m=0;m<4;m++) vv[m] = *(const float4*)&lds[m][tid*4];
  float acc[10];
  int k=0;
  #pragma unroll
  for (int i=0;i<4;i++)
    #pragma unroll
    for (int j=i;j<4;j++,k++)
      acc[k] = vv[i].x*vv[j].x + vv[i].y*vv[j].y + vv[i].z*vv[j].z + vv[i].w*vv[j].w;

  #pragma unroll
  for (int kk=0;kk<10;kk++){
    float s = acc[kk];
    #pragma unroll
    for (int off=1; off<64; off<<=1) s += __shfl_xor(s, off, 64);
    acc[kk]=s;
  }
  if (lane==0){
    #pragma unroll
    for (int kk=0;kk<10;kk++) red[w][kk] = acc[kk];
  }
  __syncthreads();
  if (tid<10){
    float s = red[0][tid] + red[1][tid] + red[2][tid] + red[3][tid];
    partials[((size_t)b*DBLK + bx)*10 + tid] = s;
  }
}

__global__ void k_attn(const float* __restrict__ partials, float* __restrict__ probs){
  __shared__ float red[4][16];
  int b = blockIdx.x, tid = threadIdx.x;       // 256 threads
  int w = tid>>6, lane = tid&63;
  float a[10];
  #pragma unroll
  for (int kk=0;kk<10;kk++) a[kk]=0.f;
  #pragma unroll
  for (int r=0;r<DBLK/256;r++){
    const float* p = partials + ((size_t)b*DBLK + r*256 + tid)*10;
    #pragma unroll
    for (int kk=0;kk<10;kk++) a[kk]+=p[kk];
  }
  #pragma unroll
  for (int kk=0;kk<10;kk++){
    float s=a[kk];
    #pragma unroll
    for (int off=1;off<64;off<<=1) s+=__shfl_xor(s,off,64);
    a[kk]=s;
  }
  if (lane==0){
    #pragma unroll
    for (int kk=0;kk<10;kk++) red[w][kk]=a[kk];
  }
  __syncthreads();
  if (tid==0){
    float d[10];
    #pragma unroll
    for (int kk=0;kk<10;kk++) d[kk]=red[0][kk]+red[1][kk]+red[2][kk]+red[3][kk];
    float D[4][4];
    int k2=0;
    #pragma unroll
    for (int i=0;i<4;i++)
      #pragma unroll
      for (int j=i;j<4;j++,k2++){ D[i][j]=d[k2]; D[j][i]=d[k2]; }
    float nrm[4];
    #pragma unroll
    for (int m=0;m<4;m++) nrm[m]=fmaxf(sqrtf(D[m][m]),1e-8f);
    float sc[4];
    #pragma unroll
    for (int i=0;i<4;i++){
      float s=0.f;
      #pragma unroll
      for (int j=0;j<4;j++) s += D[i][j]/(nrm[i]*nrm[j]);
      sc[i] = -(s-1.0f);
    }
    float mx = fmaxf(fmaxf(sc[0],sc[1]), fmaxf(sc[2],sc[3]));
    float e[4], se=0.f;
    #pragma unroll
    for (int m=0;m<4;m++){ e[m]=expf(sc[m]-mx); se+=e[m]; }
    #pragma unroll
    for (int m=0;m<4;m++) probs[b*4+m]=e[m]/se;
  }
}

// GEMM: Y[b] = (W*prob[b]) @ X[b], 2-phase double-buffered pipeline.
// Block: 256px window x 256ch, 8 chunks of [32ch][256px] staged contiguously
// (1KB/instr, padded rows). STAGE(next) issued before compute(cur); one
// vmcnt-drain barrier per chunk -> memory streams continuously.
__launch_bounds__(256, 2)
__global__ void k_gemm(const float* __restrict__ x, const float* __restrict__ w,
                       const float* __restrict__ ws, float* __restrict__ y,
                       float* __restrict__ stats){
  __shared__ float buf[2][SCH][SPX+PAD];   // 2 x 33.3 KB
  const int b   = blockIdx.y;
  const int pw  = blockIdx.x * SPX;
  const int tid = threadIdx.x;
  const int wid = tid >> 6;
  const int lane = tid & 63;
  const int l15 = lane & 15;
  const int lg  = lane >> 4;
  const int wr  = wid & 1;      // row half   (32 rows)
  const int wp  = wid >> 1;     // pixel half (128 px)

  // A fragments: rows wr*32 + rt*16 + l15; k-map (lg,el,eh) -> ch = ks*32 + lg*4 + el + 16*eh
  const float* probs = ws + 256 + b*4;
  float pm[4] = {probs[0], probs[1], probs[2], probs[3]};
  bhalf8 afrag[2][NCHK];
  const float4* w4 = reinterpret_cast<const float4*>(w);
  #pragma unroll
  for (int rt=0; rt<2; rt++){
    int row = wr*32 + rt*16 + l15;
    #pragma unroll
    for (int ks=0; ks<NCHK; ks++){
      float s = pm[ks>>1];
      float4 a0 = w4[row*64 + ks*8 + lg];
      float4 a1 = w4[row*64 + ks*8 + lg + 4];
      bhalf8 f;
      f[0]=f2bf(a0.x*s); f[1]=f2bf(a0.y*s); f[2]=f2bf(a0.z*s); f[3]=f2bf(a0.w*s);
      f[4]=f2bf(a1.x*s); f[5]=f2bf(a1.y*s); f[6]=f2bf(a1.z*s); f[7]=f2bf(a1.w*s);
      afrag[rt][ks] = f;
    }
  }

  const float* xb = x + (size_t)b*NC*HW + pw;

  // stage chunk cc into buffer cur: 32 rows, each 1KB contiguous (8 instr/wave)
  auto STAGE = [&](int cc, int cur){
    #pragma unroll
    for (int j=0; j<8; j++){
      int ch_l = wid*8 + j;
      __builtin_amdgcn_global_load_lds(
          (const __attribute__((address_space(1))) void*)(xb + (size_t)(cc*SCH + ch_l)*HW + lane*4),
          (__attribute__((address_space(3))) void*)&buf[cur][ch_l][0],
          16, 0, 0);
    }
  };

  f32x4 acc[2][8];
  #pragma unroll
  for (int rt=0; rt<2; rt++)
    #pragma unroll
    for (int pt=0; pt<8; pt++) acc[rt][pt] = (f32x4){0.f,0.f,0.f,0.f};

  STAGE(0, 0);
  __syncthreads();
  int cur = 0;
  #pragma unroll 1
  for (int cc=0; cc<NCHK; cc++){
    if (cc < NCHK-1) STAGE(cc+1, cur^1);
    const float (*bp)[SPX+PAD] = buf[cur];
    #pragma unroll
    for (int pt=0; pt<8; pt++){
      int px_l = wp*128 + pt*16 + l15;
      bhalf8 bfr;
      #pragma unroll
      for (int eh=0; eh<2; eh++)
        #pragma unroll
        for (int el=0; el<4; el++){
          int c_l = lg*4 + el + eh*16;
          bfr[eh*4+el] = f2bf(bp[c_l][px_l]);
        }
      #pragma unroll
      for (int rt=0; rt<2; rt++)
        acc[rt][pt] = __builtin_amdgcn_mfma_f32_16x16x32_bf16(afrag[rt][cc], bfr, acc[rt][pt], 0, 0, 0);
    }
    __syncthreads();          // drains vmcnt -> next buffer ready; cur safe to reuse
    cur ^= 1;
  }

  // epilogue: y write + stats (C/D: row = lg*4 + r, col = l15)
  float sacc[2][4] = {{0}}, qacc[2][4] = {{0}};
  #pragma unroll
  for (int rt=0; rt<2; rt++){
    #pragma unroll
    for (int pt=0; pt<8; pt++){
      size_t ybase = ((size_t)(b*NO + wr*32 + rt*16 + lg*4))*HW + pw + wp*128 + pt*16 + l15;
      #pragma unroll
      for (int r=0; r<4; r++){
        float v = acc[rt][pt][r];
        y[ybase + (size_t)r*HW] = v;
        sacc[rt][r] += v;
        qacc[rt][r] += v*v;
      }
    }
  }
  #pragma unroll
  for (int rt=0; rt<2; rt++){
    #pragma unroll
    for (int r=0; r<4; r++){
      float s = sacc[rt][r], q = qacc[rt][r];
      #pragma unroll
      for (int off=1; off<16; off<<=1){
        s += __shfl_xor(s, off, 64);
        q += __shfl_xor(q, off, 64);
      }
      if (l15 == 0){
        int o = wr*32 + rt*16 + lg*4 + r;
        atomicAdd(&stats[b*128 + o*2],     s);
        atomicAdd(&stats[b*128 + o*2 + 1], q);
      }
    }
  }
}

__global__ void k_norm(float* __restrict__ y, const float* __restrict__ stats){
  int bo = blockIdx.x;
  float s = stats[bo*2], q = stats[bo*2+1];
  float mean = s * (1.f/HW);
  float var  = q * (1.f/HW) - mean*mean;
  float inv  = rsqrtf(var + EPS_IN);
  float4* yp = reinterpret_cast<float4*>(y) + (size_t)bo*(HW/4);
  #pragma unroll 4
  for (int i = threadIdx.x; i < HW/4; i += 256){
    float4 v = yp[i];
    v.x = fmaxf((v.x-mean)*inv, 0.f);
    v.y = fmaxf((v.y-mean)*inv, 0.f);
    v.z = fmaxf((v.z-mean)*inv, 0.f);
    v.w = fmaxf((v.w-mean)*inv, 0.f);
    yp[i] = v;
  }
}

extern "C" void kernel_launch(void* const* d_in, const int* in_sizes, int n_in,
                              void* d_out, int out_size, void* d_ws, size_t ws_size,
                              hipStream_t stream){
  const float* x = (const float*)d_in[0];
  const float* w = (const float*)d_in[1];
  float* out = (float*)d_out;
  float* ws  = (float*)d_ws;
  float* partials = ws + 8192;
  float* probs    = ws + 256;
  float* stats    = ws + 320;

  k_zero<<<dim3(8),           dim3(256), 0, stream>>>(ws);
  k_dots<<<dim3(DBLK,16),     dim3(256), 0, stream>>>(x, partials);
  k_attn<<<dim3(16),          dim3(256), 0, stream>>>(partials, probs);
  k_gemm<<<dim3(HW/SPX,16),   dim3(256), 0, stream>>>(x, w, ws, out, stats);
  k_norm<<<dim3(1024),        dim3(256), 0, stream>>>(out, stats);
}

// Round 11
// 213.595 us; speedup vs baseline: 1.4086x; 1.0055x over previous
//
#include <hip/hip_runtime.h>
#include <hip/hip_bf16.h>

#define HW 16384
#define NC 256
#define NO 64
#define NPM 1048576          // floats per (b, modality)
#define EPS_IN 1e-5f
#define DBLK 1024            // k_dots blocks.x
#define WIN 1024             // floats per modality per window
#define SPX 256              // pixels per k_gemm block window
#define SCH 32               // channels per staged chunk (one k-slice of 32)
#define NCHK 8               // 256 / SCH
#define PAD 4                // floats of row padding in LDS

typedef float f32x4 __attribute__((ext_vector_type(4)));
typedef short bhalf8 __attribute__((ext_vector_type(8)));

static __device__ __forceinline__ short f2bf(float f){
  __bf16 h = (__bf16)f;
  return __builtin_bit_cast(short, h);
}

// ws float layout: [256,320) probs[b][m] ; [320,2368) stats[(b*64+o)*2+{s,q}] ;
//                  [8192, +16*DBLK*10) block partials

__global__ void k_zero(float* ws){
  int i = blockIdx.x*256 + threadIdx.x;
  if (i < 2048) ws[320 + i] = 0.f;   // stats only
}

// Pass 1: Gram partials. One window per block via global_load_lds (linear dest);
// latency hidden by 16384 independent blocks; per-batch skew vs stream aliasing.
__global__ void k_dots(const float* __restrict__ x, float* __restrict__ partials){
  __shared__ float lds[4][WIN];
  __shared__ float red[4][16];
  const int b = blockIdx.y, bx = blockIdx.x;
  const int tid = threadIdx.x;
  const int w = tid >> 6, lane = tid & 63;
  const int wi = (bx + b*67) & (DBLK-1);
  const float* src = x + (size_t)b*4*NPM + (size_t)w*NPM + (size_t)wi*WIN + lane*4;

  #pragma unroll
  for (int li=0; li<4; li++){
    __builtin_amdgcn_global_load_lds(
        (const __attribute__((address_space(1))) void*)(src + li*256),
        (__attribute__((address_space(3))) void*)&lds[w][li*256],
        16, 0, 0);
  }
  __syncthreads();

  float4 vv[4];
  #pragma unroll
  for (int m=0;m<4;m++) vv[m] = *(const float4*)&lds[m][tid*4];
  float acc[10];
  int k=0;
  #pragma unroll
  for (int i=0;i<4;i++)
    #pragma unroll
    for (int j=i;j<4;j++,k++)
      acc[k] = vv[i].x*vv[j].x + vv[i].y*vv[j].y + vv[i].z*vv[j].z + vv[i].w*vv[j].w;

  #pragma unroll
  for (int kk=0;kk<10;kk++){
    float s = acc[kk];
    #pragma unroll
    for (int off=1; off<64; off<<=1) s += __shfl_xor(s, off, 64);
    acc[kk]=s;
  }
  if (lane==0){
    #pragma unroll
    for (int kk=0;kk<10;kk++) red[w][kk] = acc[kk];
  }
  __syncthreads();
  if (tid<10){
    float s = red[0][tid] + red[1][tid] + red[2][tid] + red[3][tid];
    partials[((size_t)b*DBLK + bx)*10 + tid] = s;
  }
}

__global__ void k_attn(const float* __restrict__ partials, float* __restrict__ probs){
  __shared__ float red[4][16];
  int b = blockIdx.x, tid = threadIdx.x;       // 256 threads
  int w = tid>>6, lane = tid&63;
  float a[10];
  #pragma unroll
  for (int kk=0;kk<10;kk++) a[kk]=0.f;
  #pragma unroll
  for (int r=0;r<DBLK/256;r++){
    const float* p = partials + ((size_t)b*DBLK + r*256 + tid)*10;
    #pragma unroll
    for (int kk=0;kk<10;kk++) a[kk]+=p[kk];
  }
  #pragma unroll
  for (int kk=0;kk<10;kk++){
    float s=a[kk];
    #pragma unroll
    for (int off=1;off<64;off<<=1) s+=__shfl_xor(s,off,64);
    a[kk]=s;
  }
  if (lane==0){
    #pragma unroll
    for (int kk=0;kk<10;kk++) red[w][kk]=a[kk];
  }
  __syncthreads();
  if (tid==0){
    float d[10];
    #pragma unroll
    for (int kk=0;kk<10;kk++) d[kk]=red[0][kk]+red[1][kk]+red[2][kk]+red[3][kk];
    float D[4][4];
    int k2=0;
    #pragma unroll
    for (int i=0;i<4;i++)
      #pragma unroll
      for (int j=i;j<4;j++,k2++){ D[i][j]=d[k2]; D[j][i]=d[k2]; }
    float nrm[4];
    #pragma unroll
    for (int m=0;m<4;m++) nrm[m]=fmaxf(sqrtf(D[m][m]),1e-8f);
    float sc[4];
    #pragma unroll
    for (int i=0;i<4;i++){
      float s=0.f;
      #pragma unroll
      for (int j=0;j<4;j++) s += D[i][j]/(nrm[i]*nrm[j]);
      sc[i] = -(s-1.0f);
    }
    float mx = fmaxf(fmaxf(sc[0],sc[1]), fmaxf(sc[2],sc[3]));
    float e[4], se=0.f;
    #pragma unroll
    for (int m=0;m<4;m++){ e[m]=expf(sc[m]-mx); se+=e[m]; }
    #pragma unroll
    for (int m=0;m<4;m++) probs[b*4+m]=e[m]/se;
  }
}

// GEMM: Y[b] = (W*prob[b]) @ X[b]. 2-phase double-buffered pipeline with
// COUNTED vmcnt (T3+T4 minimum): raw s_barrier + s_waitcnt vmcnt(8) keeps the
// next chunk's 8 loads/wave in flight ACROSS the barrier (no __syncthreads
// vmcnt(0) drain). Per-wave own-vmcnt + barrier => all waves' LDS writes done.
__launch_bounds__(256, 2)
__global__ void k_gemm(const float* __restrict__ x, const float* __restrict__ w,
                       const float* __restrict__ ws, float* __restrict__ y,
                       float* __restrict__ stats){
  __shared__ float buf[2][SCH][SPX+PAD];   // 2 x 33.3 KB
  const int b   = blockIdx.y;
  const int pw  = blockIdx.x * SPX;
  const int tid = threadIdx.x;
  const int wid = tid >> 6;
  const int lane = tid & 63;
  const int l15 = lane & 15;
  const int lg  = lane >> 4;
  const int wr  = wid & 1;      // row half   (32 rows)
  const int wp  = wid >> 1;     // pixel half (128 px)

  // A fragments: rows wr*32 + rt*16 + l15; k-map (lg,el,eh) -> ch = ks*32 + lg*4 + el + 16*eh
  const float* probs = ws + 256 + b*4;
  float pm[4] = {probs[0], probs[1], probs[2], probs[3]};
  bhalf8 afrag[2][NCHK];
  const float4* w4 = reinterpret_cast<const float4*>(w);
  #pragma unroll
  for (int rt=0; rt<2; rt++){
    int row = wr*32 + rt*16 + l15;
    #pragma unroll
    for (int ks=0; ks<NCHK; ks++){
      float s = pm[ks>>1];
      float4 a0 = w4[row*64 + ks*8 + lg];
      float4 a1 = w4[row*64 + ks*8 + lg + 4];
      bhalf8 f;
      f[0]=f2bf(a0.x*s); f[1]=f2bf(a0.y*s); f[2]=f2bf(a0.z*s); f[3]=f2bf(a0.w*s);
      f[4]=f2bf(a1.x*s); f[5]=f2bf(a1.y*s); f[6]=f2bf(a1.z*s); f[7]=f2bf(a1.w*s);
      afrag[rt][ks] = f;
    }
  }

  const float* xb = x + (size_t)b*NC*HW + pw;

  // stage chunk cc into buffer cur: 32 rows, each 1KB contiguous (8 instr/wave)
  auto STAGE = [&](int cc, int cur){
    #pragma unroll
    for (int j=0; j<8; j++){
      int ch_l = wid*8 + j;
      __builtin_amdgcn_global_load_lds(
          (const __attribute__((address_space(1))) void*)(xb + (size_t)(cc*SCH + ch_l)*HW + lane*4),
          (__attribute__((address_space(3))) void*)&buf[cur][ch_l][0],
          16, 0, 0);
    }
  };

  f32x4 acc[2][8];
  #pragma unroll
  for (int rt=0; rt<2; rt++)
    #pragma unroll
    for (int pt=0; pt<8; pt++) acc[rt][pt] = (f32x4){0.f,0.f,0.f,0.f};

  STAGE(0, 0);
  int cur = 0;
  #pragma unroll 1
  for (int cc=0; cc<NCHK; cc++){
    if (cc < NCHK-1){
      STAGE(cc+1, cur^1);                              // 8 more loads/wave in flight
      asm volatile("s_waitcnt vmcnt(8)" ::: "memory"); // chunk cc complete; cc+1 stays in flight
    } else {
      asm volatile("s_waitcnt vmcnt(0)" ::: "memory");
    }
    __builtin_amdgcn_s_barrier();        // all waves' writes to buf[cur] done
    __builtin_amdgcn_sched_barrier(0);   // no ds_read hoisting above the wait (rule #18)

    const float (*bp)[SPX+PAD] = buf[cur];
    #pragma unroll
    for (int pt=0; pt<8; pt++){
      int px_l = wp*128 + pt*16 + l15;
      bhalf8 bfr;
      #pragma unroll
      for (int eh=0; eh<2; eh++)
        #pragma unroll
        for (int el=0; el<4; el++){
          int c_l = lg*4 + el + eh*16;
          bfr[eh*4+el] = f2bf(bp[c_l][px_l]);
        }
      #pragma unroll
      for (int rt=0; rt<2; rt++)
        acc[rt][pt] = __builtin_amdgcn_mfma_f32_16x16x32_bf16(afrag[rt][cc], bfr, acc[rt][pt], 0, 0, 0);
    }

    __builtin_amdgcn_sched_barrier(0);   // keep reads of buf[cur] before the barrier
    __builtin_amdgcn_s_barrier();        // all reads done -> buf[cur] safe to overwrite next iter
    cur ^= 1;
  }

  // epilogue: y write + stats (C/D: row = lg*4 + r, col = l15)
  float sacc[2][4] = {{0}}, qacc[2][4] = {{0}};
  #pragma unroll
  for (int rt=0; rt<2; rt++){
    #pragma unroll
    for (int pt=0; pt<8; pt++){
      size_t ybase = ((size_t)(b*NO + wr*32 + rt*16 + lg*4))*HW + pw + wp*128 + pt*16 + l15;
      #pragma unroll
      for (int r=0; r<4; r++){
        float v = acc[rt][pt][r];
        y[ybase + (size_t)r*HW] = v;
        sacc[rt][r] += v;
        qacc[rt][r] += v*v;
      }
    }
  }
  #pragma unroll
  for (int rt=0; rt<2; rt++){
    #pragma unroll
    for (int r=0; r<4; r++){
      float s = sacc[rt][r], q = qacc[rt][r];
      #pragma unroll
      for (int off=1; off<16; off<<=1){
        s += __shfl_xor(s, off, 64);
        q += __shfl_xor(q, off, 64);
      }
      if (l15 == 0){
        int o = wr*32 + rt*16 + lg*4 + r;
        atomicAdd(&stats[b*128 + o*2],     s);
        atomicAdd(&stats[b*128 + o*2 + 1], q);
      }
    }
  }
}

__global__ void k_norm(float* __restrict__ y, const float* __restrict__ stats){
  int bo = blockIdx.x;
  float s = stats[bo*2], q = stats[bo*2+1];
  float mean = s * (1.f/HW);
  float var  = q * (1.f/HW) - mean*mean;
  float inv  = rsqrtf(var + EPS_IN);
  float4* yp = reinterpret_cast<float4*>(y) + (size_t)bo*(HW/4);
  #pragma unroll 4
  for (int i = threadIdx.x; i < HW/4; i += 256){
    float4 v = yp[i];
    v.x = fmaxf((v.x-mean)*inv, 0.f);
    v.y = fmaxf((v.y-mean)*inv, 0.f);
    v.z = fmaxf((v.z-mean)*inv, 0.f);
    v.w = fmaxf((v.w-mean)*inv, 0.f);
    yp[i] = v;
  }
}

extern "C" void kernel_launch(void* const* d_in, const int* in_sizes, int n_in,
                              void* d_out, int out_size, void* d_ws, size_t ws_size,
                              hipStream_t stream){
  const float* x = (const float*)d_in[0];
  const float* w = (const float*)d_in[1];
  float* out = (float*)d_out;
  float* ws  = (float*)d_ws;
  float* partials = ws + 8192;
  float* probs    = ws + 256;
  float* stats    = ws + 320;

  k_zero<<<dim3(8),           dim3(256), 0, stream>>>(ws);
  k_dots<<<dim3(DBLK,16),     dim3(256), 0, stream>>>(x, partials);
  k_attn<<<dim3(16),          dim3(256), 0, stream>>>(partials, probs);
  k_gemm<<<dim3(HW/SPX,16),   dim3(256), 0, stream>>>(x, w, ws, out, stats);
  k_norm<<<dim3(1024),        dim3(256), 0, stream>>>(out, stats);
}